// Round 2
// baseline (16458.832 us; speedup 1.0000x reference)
//
#include <hip/hip_runtime.h>
#include <cmath>

#define NL 8
#define NR 8
#define DIM 768
#define LTOK 512
#define RTOK 512
#define EDIM 12288   // (NL+NR)*DIM

// ---------------------------------------------------------------------------
// Kernel 1: token-matching scores.  scores[i][j] = Wl . highway(|l_i - r_j|)
// (lin_tok bias omitted: constant shift, irrelevant for argmax)
//
// v2: weights read via uniform (scalar) global loads -> SGPRs, NOT LDS.
// Only l/r token tiles live in LDS.  Tile: 32 i x 16 j per block, 256 thr,
// 2 pairs/thread (rows li and li+16).  DC=16 output dims per chunk.
// Per k: 64 FMA + 3 LDS b32 -> VALU-bound.
// ---------------------------------------------------------------------------
#define DC 16
#define KC 128

__global__ __launch_bounds__(256) void scores_kernel(
    const float* __restrict__ Lg, const float* __restrict__ Rg,
    const float* __restrict__ Wn, const float* __restrict__ Wg,
    const float* __restrict__ bn, const float* __restrict__ bg,
    const float* __restrict__ Wl,
    float* __restrict__ scores)
{
    __shared__ float lT[32][KC + 4];   // stride 132 words -> bank stride 4
    __shared__ float rT[16][KC + 4];

    const int t  = threadIdx.x;
    const int i0 = blockIdx.x * 32;
    const int j0 = blockIdx.y * 16;
    const int li = t >> 4;             // 0..15 -> rows li, li+16
    const int lj = t & 15;             // 0..15

    float score0 = 0.f, score1 = 0.f;

    for (int dc = 0; dc < DIM; dc += DC) {
        float hacc[2][DC], gacc[2][DC];
#pragma unroll
        for (int d = 0; d < DC; ++d) {
            hacc[0][d] = 0.f; hacc[1][d] = 0.f;
            gacc[0][d] = 0.f; gacc[1][d] = 0.f;
        }

        for (int k0 = 0; k0 < DIM; k0 += KC) {
            __syncthreads();
            // stage L tile: 32 rows x KC (1024 float4, 4/thread)
#pragma unroll
            for (int r = 0; r < 4; ++r) {
                int idx = t + r * 256;
                int row = idx >> 5;              // 0..31
                int c4  = (idx & 31) << 2;       // 0..124
                *(float4*)&lT[row][c4] =
                    *(const float4*)(Lg + (size_t)(i0 + row) * DIM + k0 + c4);
            }
            // stage R tile: 16 rows x KC (512 float4, 2/thread)
#pragma unroll
            for (int r = 0; r < 2; ++r) {
                int idx = t + r * 256;
                int row = idx >> 5;              // 0..15
                int c4  = (idx & 31) << 2;
                *(float4*)&rT[row][c4] =
                    *(const float4*)(Rg + (size_t)(j0 + row) * DIM + k0 + c4);
            }
            __syncthreads();

            for (int k = 0; k < KC; ++k) {
                float l0 = lT[li][k];
                float l1 = lT[li + 16][k];
                float rv = rT[lj][k];
                float c0 = fabsf(l0 - rv);
                float c1 = fabsf(l1 - rv);
                // uniform addresses -> scalar loads on the SMEM pipe
                const float* wnp = Wn + (size_t)(k0 + k) * DIM + dc;
                const float* wgp = Wg + (size_t)(k0 + k) * DIM + dc;
#pragma unroll
                for (int d = 0; d < DC; ++d) {
                    float wn = wnp[d];
                    float wg = wgp[d];
                    hacc[0][d] = fmaf(c0, wn, hacc[0][d]);
                    hacc[1][d] = fmaf(c1, wn, hacc[1][d]);
                    gacc[0][d] = fmaf(c0, wg, gacc[0][d]);
                    gacc[1][d] = fmaf(c1, wg, gacc[1][d]);
                }
            }
        }

        // epilogue for this output chunk
        const float* lr0 = Lg + (size_t)(i0 + li) * DIM + dc;
        const float* lr1 = lr0 + 16 * DIM;
        const float* rr  = Rg + (size_t)(j0 + lj) * DIM + dc;
#pragma unroll
        for (int d = 0; d < DC; ++d) {
            float bnv = bn[dc + d];
            float bgv = bg[dc + d];
            float wl  = Wl[dc + d];
            float h0 = fmaxf(hacc[0][d] + bnv, 0.f);
            float h1 = fmaxf(hacc[1][d] + bnv, 0.f);
            float g0 = 1.f / (1.f + expf(-(gacc[0][d] + bgv)));
            float g1 = 1.f / (1.f + expf(-(gacc[1][d] + bgv)));
            float c0 = fabsf(lr0[d] - rr[d]);
            float c1 = fabsf(lr1[d] - rr[d]);
            score0 = fmaf(g0 * h0 + (1.f - g0) * c0, wl, score0);
            score1 = fmaf(g1 * h1 + (1.f - g1) * c1, wl, score1);
        }
    }

    scores[(size_t)(i0 + li) * RTOK + (j0 + lj)]      = score0;
    scores[(size_t)(i0 + li + 16) * RTOK + (j0 + lj)] = score1;
}

// ---------------------------------------------------------------------------
// Kernel 2: argmax per row (left tokens) and per column (right tokens).
// First-occurrence tie-break to match np.argmax.
// ---------------------------------------------------------------------------
__global__ __launch_bounds__(64) void argmax_kernel(
    const float* __restrict__ scores, int* __restrict__ idxL, int* __restrict__ idxR)
{
    const int b = blockIdx.x;          // 0..511 rows, 512..1023 cols
    const int t = threadIdx.x;
    const bool isRow = (b < LTOK);
    const int  n = b & (LTOK - 1);

    float best = -INFINITY;
    int   bidx = 0x7fffffff;
    for (int s = t; s < 512; s += 64) {
        float v = isRow ? scores[n * RTOK + s] : scores[s * RTOK + n];
        if (v > best) { best = v; bidx = s; }
    }
#pragma unroll
    for (int off = 32; off; off >>= 1) {
        float ob = __shfl_down(best, off);
        int   oi = __shfl_down(bidx, off);
        if (ob > best || (ob == best && oi < bidx)) { best = ob; bidx = oi; }
    }
    if (t == 0) (isRow ? idxL : idxR)[n] = bidx;
}

// ---------------------------------------------------------------------------
// Kernel 3: gather chosen cmp rows.
// ---------------------------------------------------------------------------
__global__ __launch_bounds__(256) void build_cmp_kernel(
    const float* __restrict__ Lg, const float* __restrict__ Rg,
    const int* __restrict__ idxL, const int* __restrict__ idxR,
    float* __restrict__ lcmp, float* __restrict__ rcmp)
{
    const int b = blockIdx.x;
    const int t = threadIdx.x;
    if (b < LTOK) {
        const float* a = Lg + b * DIM;
        const float* c = Rg + idxL[b] * DIM;
        for (int d = t; d < DIM; d += 256) lcmp[b * DIM + d] = fabsf(a[d] - c[d]);
    } else {
        const int j = b - LTOK;
        const float* a = Rg + j * DIM;
        const float* c = Lg + idxR[j] * DIM;
        for (int d = t; d < DIM; d += 256) rcmp[j * DIM + d] = fabsf(a[d] - c[d]);
    }
}

// ---------------------------------------------------------------------------
// Kernel 4: attribute matching (ragged segment softmax + weighted cmp sum).
// One block per (side, attr).  Writes directly into concat layout x[16*768].
// ---------------------------------------------------------------------------
__global__ __launch_bounds__(256) void attr_match_kernel(
    const float* __restrict__ Lg, const float* __restrict__ Rg,
    const float* __restrict__ lcmp, const float* __restrict__ rcmp,
    const int* __restrict__ lensL, const int* __restrict__ lensR,
    const float* __restrict__ embL, const float* __restrict__ embR,
    const float* __restrict__ emptyRes,
    float* __restrict__ x)
{
    __shared__ float logits[512];
    __shared__ float red[256];

    const int b    = blockIdx.x;
    const int side = b >> 3;
    const int a    = b & 7;
    const int t    = threadIdx.x;

    const int*   lens = side ? lensR : lensL;
    const float* toks = side ? Rg   : Lg;
    const float* cmp  = side ? rcmp : lcmp;
    const float* femb = (side ? embR : embL) + a * DIM;
    float* outp = x + (side * 8 + a) * DIM;

    int start = 0;
    for (int q = 0; q < a; ++q) start += lens[q];
    const int len = lens[a];

    if (len == 0) {
        for (int d = t; d < DIM; d += 256) outp[d] = emptyRes[d];
        return;
    }

    // per-token logits: dot(token, attr_emb)
    for (int tok = t; tok < len; tok += 256) {
        const float* tr = toks + (start + tok) * DIM;
        float s = 0.f;
        for (int d = 0; d < DIM; ++d) s = fmaf(tr[d], femb[d], s);
        logits[tok] = s;
    }
    __syncthreads();

    // max
    float m = -INFINITY;
    for (int tok = t; tok < len; tok += 256) m = fmaxf(m, logits[tok]);
    red[t] = m; __syncthreads();
    for (int off = 128; off; off >>= 1) {
        if (t < off) red[t] = fmaxf(red[t], red[t + off]);
        __syncthreads();
    }
    m = red[0]; __syncthreads();

    // exp + sum (store exp back into logits)
    float sum = 0.f;
    for (int tok = t; tok < len; tok += 256) {
        float e = expf(logits[tok] - m);
        logits[tok] = e;
        sum += e;
    }
    red[t] = sum; __syncthreads();
    for (int off = 128; off; off >>= 1) {
        if (t < off) red[t] += red[t + off];
        __syncthreads();
    }
    const float inv = 1.f / red[0];
    __syncthreads();

    // weighted sum of cmp rows
    for (int d = t; d < DIM; d += 256) {
        float acc = 0.f;
        for (int tok = 0; tok < len; ++tok)
            acc = fmaf(logits[tok] * inv, cmp[(start + tok) * DIM + d], acc);
        outp[d] = acc;
    }
}

// ---------------------------------------------------------------------------
// Kernel 5: entity highway matvec partials (split-K, deterministic).
// grid (12 out-blocks x 32 in-slabs x 2 mats); each thread: 4 outputs (float4).
// ---------------------------------------------------------------------------
__global__ __launch_bounds__(256) void ent_partial_kernel(
    const float* __restrict__ Wn, const float* __restrict__ Wg,
    const float* __restrict__ x, float* __restrict__ partial)
{
    __shared__ float xs[384];
    const int ob   = blockIdx.x;   // 12
    const int slab = blockIdx.y;   // 32
    const int mat  = blockIdx.z;   // 2
    const float* W = mat ? Wg : Wn;
    const int t  = threadIdx.x;
    const int o0 = ob * 1024 + t * 4;
    const int in0 = slab * 384;

    for (int i = t; i < 384; i += 256) xs[i] = x[in0 + i];
    __syncthreads();

    float4 acc = {0.f, 0.f, 0.f, 0.f};
    for (int in = 0; in < 384; ++in) {
        const float  xv = xs[in];
        const float4 w  = *(const float4*)(W + (size_t)(in0 + in) * EDIM + o0);
        acc.x = fmaf(xv, w.x, acc.x);
        acc.y = fmaf(xv, w.y, acc.y);
        acc.z = fmaf(xv, w.z, acc.z);
        acc.w = fmaf(xv, w.w, acc.w);
    }
    *(float4*)(partial + ((size_t)mat * 32 + slab) * EDIM + o0) = acc;
}

// ---------------------------------------------------------------------------
// Kernel 6: reduce the 32 split-K partials.
// ---------------------------------------------------------------------------
__global__ __launch_bounds__(256) void ent_reduce_kernel(
    const float* __restrict__ partial, float* __restrict__ hsum)
{
    const int mat = blockIdx.y;
    const int o   = blockIdx.x * 1024 + threadIdx.x * 4;
    float4 acc = {0.f, 0.f, 0.f, 0.f};
    for (int s = 0; s < 32; ++s) {
        const float4 p = *(const float4*)(partial + ((size_t)mat * 32 + s) * EDIM + o);
        acc.x += p.x; acc.y += p.y; acc.z += p.z; acc.w += p.w;
    }
    *(float4*)(hsum + (size_t)mat * EDIM + o) = acc;
}

// ---------------------------------------------------------------------------
// Kernel 7: entity highway epilogue + final linear + softmax.
// ---------------------------------------------------------------------------
__global__ __launch_bounds__(256) void finalize_kernel(
    const float* __restrict__ hsum, const float* __restrict__ x,
    const float* __restrict__ bn, const float* __restrict__ bg,
    const float* __restrict__ Wl2, const float* __restrict__ bl2,
    float* __restrict__ out)
{
    __shared__ float r0[256], r1[256];
    const int t = threadIdx.x;
    float l0 = 0.f, l1 = 0.f;
    for (int d = t; d < EDIM; d += 256) {
        float h  = fmaxf(hsum[d] + bn[d], 0.f);
        float gv = 1.f / (1.f + expf(-(hsum[EDIM + d] + bg[d])));
        float hw = gv * h + (1.f - gv) * x[d];
        l0 = fmaf(hw, Wl2[d * 2 + 0], l0);
        l1 = fmaf(hw, Wl2[d * 2 + 1], l1);
    }
    r0[t] = l0; r1[t] = l1; __syncthreads();
    for (int off = 128; off; off >>= 1) {
        if (t < off) { r0[t] += r0[t + off]; r1[t] += r1[t + off]; }
        __syncthreads();
    }
    if (t == 0) {
        float a = r0[0] + bl2[0];
        float b = r1[0] + bl2[1];
        float m  = fmaxf(a, b);
        float ea = expf(a - m), eb = expf(b - m);
        float inv = 1.f / (ea + eb);
        out[0] = ea * inv;
        out[1] = eb * inv;
    }
}

// ---------------------------------------------------------------------------
extern "C" void kernel_launch(void* const* d_in, const int* in_sizes, int n_in,
                              void* d_out, int out_size, void* d_ws, size_t ws_size,
                              hipStream_t stream)
{
    const float* Lg     = (const float*)d_in[0];
    const float* Rg     = (const float*)d_in[1];
    const int*   lensL  = (const int*)  d_in[2];
    const int*   lensR  = (const int*)  d_in[3];
    const float* tWn    = (const float*)d_in[4];
    const float* tbn    = (const float*)d_in[5];
    const float* tWg    = (const float*)d_in[6];
    const float* tbg    = (const float*)d_in[7];
    const float* tWl    = (const float*)d_in[8];
    // d_in[9] = lin_tok_b : constant score shift, irrelevant to argmax
    const float* embL   = (const float*)d_in[10];
    const float* embR   = (const float*)d_in[11];
    const float* eWn    = (const float*)d_in[12];
    const float* ebn    = (const float*)d_in[13];
    const float* eWg    = (const float*)d_in[14];
    const float* ebg    = (const float*)d_in[15];
    const float* eWl    = (const float*)d_in[16];
    const float* ebl    = (const float*)d_in[17];
    const float* emptyR = (const float*)d_in[18];
    float* out = (float*)d_out;

    // workspace layout
    char* ws = (char*)d_ws;
    float* scores  = (float*)(ws);                               // 512*512
    int*   idxL    = (int*)  (ws + (size_t)1048576);             // 512
    int*   idxR    = idxL + 512;                                 // 512
    float* lcmp    = (float*)(ws + (size_t)1048576 + 4096);      // 512*768
    float* rcmp    = lcmp + (size_t)LTOK * DIM;                  // 512*768
    float* xcat    = rcmp + (size_t)RTOK * DIM;                  // 12288
    float* partial = xcat + EDIM;                                // 2*32*12288
    float* hsum    = partial + (size_t)2 * 32 * EDIM;            // 2*12288

    scores_kernel<<<dim3(LTOK / 32, RTOK / 16), 256, 0, stream>>>(
        Lg, Rg, tWn, tWg, tbn, tbg, tWl, scores);

    argmax_kernel<<<dim3(LTOK + RTOK), 64, 0, stream>>>(scores, idxL, idxR);

    build_cmp_kernel<<<dim3(LTOK + RTOK), 256, 0, stream>>>(
        Lg, Rg, idxL, idxR, lcmp, rcmp);

    attr_match_kernel<<<dim3(16), 256, 0, stream>>>(
        Lg, Rg, lcmp, rcmp, lensL, lensR, embL, embR, emptyR, xcat);

    ent_partial_kernel<<<dim3(EDIM / 1024, 32, 2), 256, 0, stream>>>(
        eWn, eWg, xcat, partial);

    ent_reduce_kernel<<<dim3(EDIM / 1024, 2), 256, 0, stream>>>(partial, hsum);

    finalize_kernel<<<dim3(1), 256, 0, stream>>>(
        hsum, xcat, ebn, ebg, eWl, ebl, out);
}

// Round 3
// 7395.210 us; speedup vs baseline: 2.2256x; 2.2256x over previous
//
#include <hip/hip_runtime.h>
#include <cmath>

#define NL 8
#define NR 8
#define DIM 768
#define LTOK 512
#define RTOK 512
#define EDIM 12288   // (NL+NR)*DIM

// ---------------------------------------------------------------------------
// Kernel 1: token-matching scores (register-tiled GEMM structure).
//   scores[i][j] = sum_d Wl[d] * highway_d(|l_i - r_j|)
//   hacc[p][d] = sum_k |l_i[k]-r_j[k]| * Wn[k][d]   (+ same for Wg)
//
// Block: 256 thr = 16x16, each thread 4i x 2j = 8 pairs, DC=8 d per chunk.
// Per k-iter: 128 FMA + 8 sub + 6 LDS b32 (broadcast) + 4 LDS b128 (uniform).
// Grid: (512/64) x (512/32) x 4 d-splits = 512 blocks = 2/CU.
// Partial scores per d-split; summed by sum_scores_kernel.
// ---------------------------------------------------------------------------
#define DCB 192   // d-range per block (4 splits x 192 = 768)
#define DC  8     // d per register chunk
#define KC  128   // k per LDS stage
#define TI  4
#define TJ  2

__global__ __launch_bounds__(256, 2) void scores_kernel(
    const float* __restrict__ Lg, const float* __restrict__ Rg,
    const float* __restrict__ Wn, const float* __restrict__ Wg,
    const float* __restrict__ bn, const float* __restrict__ bg,
    const float* __restrict__ Wl,
    float* __restrict__ scores_p)
{
    __shared__ float lT[64][KC + 1];   // +1 pad: broadcast reads conflict-free
    __shared__ float rT[32][KC + 1];
    __shared__ float wnT[KC][DC];      // uniform-address reads (broadcast)
    __shared__ float wgT[KC][DC];

    const int t   = threadIdx.x;
    const int i0  = blockIdx.x * 64;
    const int j0  = blockIdx.y * 32;
    const int dsp = blockIdx.z;        // 0..3
    const int ti  = t >> 4;            // 0..15
    const int tj  = t & 15;            // 0..15

    float score[TI][TJ];
#pragma unroll
    for (int a = 0; a < TI; ++a)
#pragma unroll
        for (int b = 0; b < TJ; ++b) score[a][b] = 0.f;

    for (int sub = 0; sub < DCB / DC; ++sub) {
        const int dg = dsp * DCB + sub * DC;

        float hacc[TI][TJ][DC], gacc[TI][TJ][DC];
#pragma unroll
        for (int a = 0; a < TI; ++a)
#pragma unroll
            for (int b = 0; b < TJ; ++b)
#pragma unroll
                for (int d = 0; d < DC; ++d) { hacc[a][b][d] = 0.f; gacc[a][b][d] = 0.f; }

        for (int k0 = 0; k0 < DIM; k0 += KC) {
            __syncthreads();
            // stage L tile: 64 rows x KC  (2048 float4, 8/thread, coalesced)
#pragma unroll
            for (int r = 0; r < 8; ++r) {
                int idx = t + r * 256;
                int row = idx >> 5;
                int c4  = (idx & 31) << 2;
                *(float4*)&lT[row][c4] =
                    *(const float4*)(Lg + (size_t)(i0 + row) * DIM + k0 + c4);
            }
            // stage R tile: 32 rows x KC  (1024 float4, 4/thread)
#pragma unroll
            for (int r = 0; r < 4; ++r) {
                int idx = t + r * 256;
                int row = idx >> 5;
                int c4  = (idx & 31) << 2;
                *(float4*)&rT[row][c4] =
                    *(const float4*)(Rg + (size_t)(j0 + row) * DIM + k0 + c4);
            }
            // stage weight slabs: KC x DC each (256 float4 per matrix, 1/thread)
            {
                int k  = t >> 1;
                int d4 = (t & 1) * 4;
                *(float4*)&wnT[k][d4] = *(const float4*)(Wn + (size_t)(k0 + k) * DIM + dg + d4);
                *(float4*)&wgT[k][d4] = *(const float4*)(Wg + (size_t)(k0 + k) * DIM + dg + d4);
            }
            __syncthreads();

#pragma unroll 2
            for (int k = 0; k < KC; ++k) {
                float lv[TI], rv[TJ];
#pragma unroll
                for (int a = 0; a < TI; ++a) lv[a] = lT[ti * TI + a][k];
#pragma unroll
                for (int b = 0; b < TJ; ++b) rv[b] = rT[tj * TJ + b][k];
                float wn[DC], wg[DC];
#pragma unroll
                for (int d = 0; d < DC; ++d) { wn[d] = wnT[k][d]; wg[d] = wgT[k][d]; }
#pragma unroll
                for (int a = 0; a < TI; ++a)
#pragma unroll
                    for (int b = 0; b < TJ; ++b) {
                        float c = fabsf(lv[a] - rv[b]);   // abs folds into FMA src mod
#pragma unroll
                        for (int d = 0; d < DC; ++d) {
                            hacc[a][b][d] = fmaf(c, wn[d], hacc[a][b][d]);
                            gacc[a][b][d] = fmaf(c, wg[d], gacc[a][b][d]);
                        }
                    }
            }
        }

        // epilogue for this d-chunk (L2-hot global reads; uniform bias reads)
#pragma unroll
        for (int a = 0; a < TI; ++a) {
            const int i = i0 + ti * TI + a;
            float lep[DC];
#pragma unroll
            for (int d = 0; d < DC; ++d) lep[d] = Lg[(size_t)i * DIM + dg + d];
#pragma unroll
            for (int b = 0; b < TJ; ++b) {
                const int j = j0 + tj * TJ + b;
                float s = score[a][b];
#pragma unroll
                for (int d = 0; d < DC; ++d) {
                    float h  = fmaxf(hacc[a][b][d] + bn[dg + d], 0.f);
                    float gv = 1.f / (1.f + expf(-(gacc[a][b][d] + bg[dg + d])));
                    float c  = fabsf(lep[d] - Rg[(size_t)j * DIM + dg + d]);
                    s = fmaf(gv * h + (1.f - gv) * c, Wl[dg + d], s);
                }
                score[a][b] = s;
            }
        }
    }

#pragma unroll
    for (int a = 0; a < TI; ++a)
#pragma unroll
        for (int b = 0; b < TJ; ++b)
            scores_p[((size_t)dsp * LTOK + i0 + ti * TI + a) * RTOK + j0 + tj * TJ + b] =
                score[a][b];
}

// ---------------------------------------------------------------------------
// Kernel 1b: sum the 4 d-split partial score planes.
// ---------------------------------------------------------------------------
__global__ __launch_bounds__(256) void sum_scores_kernel(
    const float* __restrict__ sp, float* __restrict__ s)
{
    const int idx = blockIdx.x * 256 + threadIdx.x;   // grid 1024 -> 262144
    const size_t P = (size_t)LTOK * RTOK;
    s[idx] = ((sp[idx] + sp[P + idx]) + (sp[2 * P + idx] + sp[3 * P + idx]));
}

// ---------------------------------------------------------------------------
// Kernel 2: argmax per row (left) and per column (right); first-occurrence ties.
// ---------------------------------------------------------------------------
__global__ __launch_bounds__(64) void argmax_kernel(
    const float* __restrict__ scores, int* __restrict__ idxL, int* __restrict__ idxR)
{
    const int b = blockIdx.x;          // 0..511 rows, 512..1023 cols
    const int t = threadIdx.x;
    const bool isRow = (b < LTOK);
    const int  n = b & (LTOK - 1);

    float best = -INFINITY;
    int   bidx = 0x7fffffff;
    for (int s = t; s < 512; s += 64) {
        float v = isRow ? scores[n * RTOK + s] : scores[s * RTOK + n];
        if (v > best) { best = v; bidx = s; }
    }
#pragma unroll
    for (int off = 32; off; off >>= 1) {
        float ob = __shfl_down(best, off);
        int   oi = __shfl_down(bidx, off);
        if (ob > best || (ob == best && oi < bidx)) { best = ob; bidx = oi; }
    }
    if (t == 0) (isRow ? idxL : idxR)[n] = bidx;
}

// ---------------------------------------------------------------------------
// Kernel 3: gather chosen cmp rows.
// ---------------------------------------------------------------------------
__global__ __launch_bounds__(256) void build_cmp_kernel(
    const float* __restrict__ Lg, const float* __restrict__ Rg,
    const int* __restrict__ idxL, const int* __restrict__ idxR,
    float* __restrict__ lcmp, float* __restrict__ rcmp)
{
    const int b = blockIdx.x;
    const int t = threadIdx.x;
    if (b < LTOK) {
        const float* a = Lg + b * DIM;
        const float* c = Rg + idxL[b] * DIM;
        for (int d = t; d < DIM; d += 256) lcmp[b * DIM + d] = fabsf(a[d] - c[d]);
    } else {
        const int j = b - LTOK;
        const float* a = Rg + j * DIM;
        const float* c = Lg + idxR[j] * DIM;
        for (int d = t; d < DIM; d += 256) rcmp[j * DIM + d] = fabsf(a[d] - c[d]);
    }
}

// ---------------------------------------------------------------------------
// Kernel 4: attribute matching (ragged segment softmax + weighted cmp sum).
// ---------------------------------------------------------------------------
__global__ __launch_bounds__(256) void attr_match_kernel(
    const float* __restrict__ Lg, const float* __restrict__ Rg,
    const float* __restrict__ lcmp, const float* __restrict__ rcmp,
    const int* __restrict__ lensL, const int* __restrict__ lensR,
    const float* __restrict__ embL, const float* __restrict__ embR,
    const float* __restrict__ emptyRes,
    float* __restrict__ x)
{
    __shared__ float logits[512];
    __shared__ float red[256];

    const int b    = blockIdx.x;
    const int side = b >> 3;
    const int a    = b & 7;
    const int t    = threadIdx.x;

    const int*   lens = side ? lensR : lensL;
    const float* toks = side ? Rg   : Lg;
    const float* cmp  = side ? rcmp : lcmp;
    const float* femb = (side ? embR : embL) + a * DIM;
    float* outp = x + (side * 8 + a) * DIM;

    int start = 0;
    for (int q = 0; q < a; ++q) start += lens[q];
    const int len = lens[a];

    if (len == 0) {
        for (int d = t; d < DIM; d += 256) outp[d] = emptyRes[d];
        return;
    }

    for (int tok = t; tok < len; tok += 256) {
        const float* tr = toks + (start + tok) * DIM;
        float s = 0.f;
        for (int d = 0; d < DIM; ++d) s = fmaf(tr[d], femb[d], s);
        logits[tok] = s;
    }
    __syncthreads();

    float m = -INFINITY;
    for (int tok = t; tok < len; tok += 256) m = fmaxf(m, logits[tok]);
    red[t] = m; __syncthreads();
    for (int off = 128; off; off >>= 1) {
        if (t < off) red[t] = fmaxf(red[t], red[t + off]);
        __syncthreads();
    }
    m = red[0]; __syncthreads();

    float sum = 0.f;
    for (int tok = t; tok < len; tok += 256) {
        float e = expf(logits[tok] - m);
        logits[tok] = e;
        sum += e;
    }
    red[t] = sum; __syncthreads();
    for (int off = 128; off; off >>= 1) {
        if (t < off) red[t] += red[t + off];
        __syncthreads();
    }
    const float inv = 1.f / red[0];
    __syncthreads();

    for (int d = t; d < DIM; d += 256) {
        float acc = 0.f;
        for (int tok = 0; tok < len; ++tok)
            acc = fmaf(logits[tok] * inv, cmp[(start + tok) * DIM + d], acc);
        outp[d] = acc;
    }
}

// ---------------------------------------------------------------------------
// Kernel 5: entity highway matvec partials (split-K, deterministic).
// ---------------------------------------------------------------------------
__global__ __launch_bounds__(256) void ent_partial_kernel(
    const float* __restrict__ Wn, const float* __restrict__ Wg,
    const float* __restrict__ x, float* __restrict__ partial)
{
    __shared__ float xs[384];
    const int ob   = blockIdx.x;   // 12
    const int slab = blockIdx.y;   // 32
    const int mat  = blockIdx.z;   // 2
    const float* W = mat ? Wg : Wn;
    const int t  = threadIdx.x;
    const int o0 = ob * 1024 + t * 4;
    const int in0 = slab * 384;

    for (int i = t; i < 384; i += 256) xs[i] = x[in0 + i];
    __syncthreads();

    float4 acc = {0.f, 0.f, 0.f, 0.f};
    for (int in = 0; in < 384; ++in) {
        const float  xv = xs[in];
        const float4 w  = *(const float4*)(W + (size_t)(in0 + in) * EDIM + o0);
        acc.x = fmaf(xv, w.x, acc.x);
        acc.y = fmaf(xv, w.y, acc.y);
        acc.z = fmaf(xv, w.z, acc.z);
        acc.w = fmaf(xv, w.w, acc.w);
    }
    *(float4*)(partial + ((size_t)mat * 32 + slab) * EDIM + o0) = acc;
}

// ---------------------------------------------------------------------------
// Kernel 6: reduce the 32 split-K partials.
// ---------------------------------------------------------------------------
__global__ __launch_bounds__(256) void ent_reduce_kernel(
    const float* __restrict__ partial, float* __restrict__ hsum)
{
    const int mat = blockIdx.y;
    const int o   = blockIdx.x * 1024 + threadIdx.x * 4;
    float4 acc = {0.f, 0.f, 0.f, 0.f};
    for (int s = 0; s < 32; ++s) {
        const float4 p = *(const float4*)(partial + ((size_t)mat * 32 + s) * EDIM + o);
        acc.x += p.x; acc.y += p.y; acc.z += p.z; acc.w += p.w;
    }
    *(float4*)(hsum + (size_t)mat * EDIM + o) = acc;
}

// ---------------------------------------------------------------------------
// Kernel 7: entity highway epilogue + final linear + softmax.
// ---------------------------------------------------------------------------
__global__ __launch_bounds__(256) void finalize_kernel(
    const float* __restrict__ hsum, const float* __restrict__ x,
    const float* __restrict__ bn, const float* __restrict__ bg,
    const float* __restrict__ Wl2, const float* __restrict__ bl2,
    float* __restrict__ out)
{
    __shared__ float r0[256], r1[256];
    const int t = threadIdx.x;
    float l0 = 0.f, l1 = 0.f;
    for (int d = t; d < EDIM; d += 256) {
        float h  = fmaxf(hsum[d] + bn[d], 0.f);
        float gv = 1.f / (1.f + expf(-(hsum[EDIM + d] + bg[d])));
        float hw = gv * h + (1.f - gv) * x[d];
        l0 = fmaf(hw, Wl2[d * 2 + 0], l0);
        l1 = fmaf(hw, Wl2[d * 2 + 1], l1);
    }
    r0[t] = l0; r1[t] = l1; __syncthreads();
    for (int off = 128; off; off >>= 1) {
        if (t < off) { r0[t] += r0[t + off]; r1[t] += r1[t + off]; }
        __syncthreads();
    }
    if (t == 0) {
        float a = r0[0] + bl2[0];
        float b = r1[0] + bl2[1];
        float m  = fmaxf(a, b);
        float ea = expf(a - m), eb = expf(b - m);
        float inv = 1.f / (ea + eb);
        out[0] = ea * inv;
        out[1] = eb * inv;
    }
}

// ---------------------------------------------------------------------------
extern "C" void kernel_launch(void* const* d_in, const int* in_sizes, int n_in,
                              void* d_out, int out_size, void* d_ws, size_t ws_size,
                              hipStream_t stream)
{
    const float* Lg     = (const float*)d_in[0];
    const float* Rg     = (const float*)d_in[1];
    const int*   lensL  = (const int*)  d_in[2];
    const int*   lensR  = (const int*)  d_in[3];
    const float* tWn    = (const float*)d_in[4];
    const float* tbn    = (const float*)d_in[5];
    const float* tWg    = (const float*)d_in[6];
    const float* tbg    = (const float*)d_in[7];
    const float* tWl    = (const float*)d_in[8];
    // d_in[9] = lin_tok_b : constant score shift, irrelevant to argmax
    const float* embL   = (const float*)d_in[10];
    const float* embR   = (const float*)d_in[11];
    const float* eWn    = (const float*)d_in[12];
    const float* ebn    = (const float*)d_in[13];
    const float* eWg    = (const float*)d_in[14];
    const float* ebg    = (const float*)d_in[15];
    const float* eWl    = (const float*)d_in[16];
    const float* ebl    = (const float*)d_in[17];
    const float* emptyR = (const float*)d_in[18];
    float* out = (float*)d_out;

    // workspace layout (bytes)
    //   [0, 4MB)        scores_p (4 x 512 x 512)   -- later aliased by ent partial/hsum
    //   [4MB, 5MB)      scores dense
    //   [5MB, +4KB)     idxL/idxR
    //   then lcmp, rcmp, xcat
    char* ws = (char*)d_ws;
    const size_t P = (size_t)LTOK * RTOK;
    float* scores_p = (float*)ws;                                  // 4 MB
    float* scores   = (float*)(ws + 4 * P * 4);                    // 1 MB
    int*   idxL     = (int*)  (ws + 5 * P * 4);                    // 2 KB
    int*   idxR     = idxL + 512;
    float* lcmp     = (float*)(ws + 5 * P * 4 + 4096);             // 1.5 MB
    float* rcmp     = lcmp + (size_t)LTOK * DIM;                   // 1.5 MB
    float* xcat     = rcmp + (size_t)RTOK * DIM;                   // 48 KB
    // aliases into the dead scores_p region (scores_p consumed by sum kernel)
    float* partial  = (float*)ws;                                  // 3 MB
    float* hsum     = (float*)(ws + (size_t)2 * 32 * EDIM * 4);    // 96 KB (still < 4MB)

    scores_kernel<<<dim3(LTOK / 64, RTOK / 32, 4), 256, 0, stream>>>(
        Lg, Rg, tWn, tWg, tbn, tbg, tWl, scores_p);

    sum_scores_kernel<<<dim3(P / 256), 256, 0, stream>>>(scores_p, scores);

    argmax_kernel<<<dim3(LTOK + RTOK), 64, 0, stream>>>(scores, idxL, idxR);

    build_cmp_kernel<<<dim3(LTOK + RTOK), 256, 0, stream>>>(
        Lg, Rg, idxL, idxR, lcmp, rcmp);

    attr_match_kernel<<<dim3(16), 256, 0, stream>>>(
        Lg, Rg, lcmp, rcmp, lensL, lensR, embL, embR, emptyR, xcat);

    ent_partial_kernel<<<dim3(EDIM / 1024, 32, 2), 256, 0, stream>>>(
        eWn, eWg, xcat, partial);

    ent_reduce_kernel<<<dim3(EDIM / 1024, 2), 256, 0, stream>>>(partial, hsum);

    finalize_kernel<<<dim3(1), 256, 0, stream>>>(
        hsum, xcat, ebn, ebg, eWl, ebl, out);
}

// Round 4
// 2416.449 us; speedup vs baseline: 6.8112x; 3.0604x over previous
//
#include <hip/hip_runtime.h>
#include <cmath>

#define NL 8
#define NR 8
#define DIM 768
#define LTOK 512
#define RTOK 512
#define EDIM 12288   // (NL+NR)*DIM

typedef unsigned short u16;
typedef __bf16 bf16x8 __attribute__((ext_vector_type(8)));
typedef float  f32x4  __attribute__((ext_vector_type(4)));

#define WARR 589824          // 768*768 elements per split array
// frag-major layout for W (per array): idx(k,d) = (((k>>5)*4 + ((k>>3)&3))*768 + d)*8 + (k&7)

// RNE split of f32 into bf16 hi + bf16 lo (x ~= hi + lo, |lo| <= 2^-9 |x|)
__device__ __forceinline__ void splitbf(float c, u16& hi, u16& lo) {
    unsigned u  = __builtin_bit_cast(unsigned, c);
    unsigned hb = (u + 0x7FFFu + ((u >> 16) & 1u)) & 0xFFFF0000u;
    hi = (u16)(hb >> 16);
    float l = c - __builtin_bit_cast(float, hb);
    unsigned ul = __builtin_bit_cast(unsigned, l);
    lo = (u16)((ul + 0x7FFFu + ((ul >> 16) & 1u)) >> 16);
}

// ---------------------------------------------------------------------------
// Kernel 0: pre-split token-matching weights into bf16 hi/lo, frag-major.
// out: [wn_hi | wn_lo | wg_hi | wg_lo], each WARR u16.
// ---------------------------------------------------------------------------
__global__ __launch_bounds__(256) void wsplit_kernel(
    const float* __restrict__ Wn, const float* __restrict__ Wg, u16* __restrict__ out)
{
    const int d = blockIdx.x * 256 + threadIdx.x;   // grid.x = 3
    const int k = blockIdx.y;                       // grid.y = 768
    const size_t src = (size_t)k * DIM + d;
    const size_t fo  = ((size_t)((k >> 5) * 4 + ((k >> 3) & 3)) * DIM + d) * 8 + (k & 7);
    u16 h, l;
    splitbf(Wn[src], h, l);
    out[fo] = h; out[WARR + fo] = l;
    splitbf(Wg[src], h, l);
    out[2 * WARR + fo] = h; out[3 * WARR + fo] = l;
}

// ---------------------------------------------------------------------------
// Kernel 1: token-matching scores via bf16x3 split MFMA (16x16x32).
//   hacc[p][d] = sum_k |l_i[k]-r_j[k]| * Wn[k][d]   (+ same for Wg)
//   score[p]   = sum_d Wl[d] * highway_d(...)
//
// Block: 256 thr = 4 waves; wave w owns column j = j0+w, 64 i-rows as
// 4 MFMA A-tiles of 16. D swept in chunks of 64 (12 sweeps), K staged 64.
// Per k32 per wave: gen 32 cmp el/lane (hi/lo) + 16 B-frag b128 + 96 MFMA.
// ---------------------------------------------------------------------------
__global__ __launch_bounds__(256, 2) void scores_kernel(
    const float* __restrict__ Lg, const float* __restrict__ Rg,
    const u16* __restrict__ wfrag,
    const float* __restrict__ bn, const float* __restrict__ bg,
    const float* __restrict__ Wl,
    float* __restrict__ scores)
{
    __shared__ float lT[64][66];     // 64 i-rows x 64 k (pad 2 -> b64-friendly)
    __shared__ float rT[4][66];      // 4 j-rows
    __shared__ u16   wLDS[16384];    // [arr4][kc2][q4][d64][e8]

    const int t    = threadIdx.x;
    const int lane = t & 63;
    const int wid  = t >> 6;
    const int l15  = lane & 15;
    const int q16  = lane >> 4;
    const int i0   = blockIdx.x * 64;
    const int j    = blockIdx.y * 4 + wid;

    float sacc[4][4];
#pragma unroll
    for (int a = 0; a < 4; ++a)
#pragma unroll
        for (int r = 0; r < 4; ++r) sacc[a][r] = 0.f;

    for (int sweep = 0; sweep < 12; ++sweep) {
        const int dg = sweep * 64;
        f32x4 acc[4][2][4];
#pragma unroll
        for (int a = 0; a < 4; ++a)
#pragma unroll
            for (int m = 0; m < 2; ++m)
#pragma unroll
                for (int n = 0; n < 4; ++n) acc[a][m][n] = (f32x4){0.f, 0.f, 0.f, 0.f};

        for (int k0 = 0; k0 < DIM; k0 += 64) {
            __syncthreads();
            // stage W frags: 32KB, linear copy, coalesced 16B per thread x8
            {
                const int k32b = k0 >> 5;
#pragma unroll
                for (int it = 0; it < 8; ++it) {
                    int lidx   = it * 256 + t;        // 16B units
                    int chunk  = lidx >> 6;           // 32 x 1KB chunks
                    int within = lidx & 63;           // d-local
                    int a = chunk >> 3, kcl = (chunk >> 2) & 1, q = chunk & 3;
                    const u16* src = wfrag + (size_t)a * WARR +
                        ((size_t)((k32b + kcl) * 4 + q) * DIM + dg + within) * 8;
                    *(float4*)&wLDS[lidx * 8] = *(const float4*)src;
                }
            }
            // stage lT: 64 rows x 64 f32
#pragma unroll
            for (int it = 0; it < 4; ++it) {
                int lidx = it * 256 + t;
                int row = lidx >> 4, c4 = (lidx & 15) * 4;
                float4 v = *(const float4*)(Lg + (size_t)(i0 + row) * DIM + k0 + c4);
                lT[row][c4] = v.x; lT[row][c4 + 1] = v.y;
                lT[row][c4 + 2] = v.z; lT[row][c4 + 3] = v.w;
            }
            // stage rT: 4 rows x 64 f32
            {
                int row = t >> 6, c = t & 63;
                rT[row][c] = Rg[(size_t)(blockIdx.y * 4 + row) * DIM + k0 + c];
            }
            __syncthreads();

#pragma unroll
            for (int kc = 0; kc < 2; ++kc) {
                const int koff = kc * 32 + q16 * 8;
                float rv[8];
#pragma unroll
                for (int e = 0; e < 8; e += 2) {
                    float2 p = *(const float2*)&rT[wid][koff + e];
                    rv[e] = p.x; rv[e + 1] = p.y;
                }
                bf16x8 ah[4], al[4];
#pragma unroll
                for (int tile = 0; tile < 4; ++tile) {
                    const float* lrow = &lT[tile * 16 + l15][0];
#pragma unroll
                    for (int e = 0; e < 8; e += 2) {
                        float2 lp = *(const float2*)&lrow[koff + e];
                        u16 h0, o0, h1, o1;
                        splitbf(fabsf(lp.x - rv[e]),     h0, o0);
                        splitbf(fabsf(lp.y - rv[e + 1]), h1, o1);
                        ah[tile][e]     = __builtin_bit_cast(__bf16, h0);
                        ah[tile][e + 1] = __builtin_bit_cast(__bf16, h1);
                        al[tile][e]     = __builtin_bit_cast(__bf16, o0);
                        al[tile][e + 1] = __builtin_bit_cast(__bf16, o1);
                    }
                }
#pragma unroll
                for (int mat = 0; mat < 2; ++mat)
#pragma unroll
                    for (int nt = 0; nt < 4; ++nt) {
                        const int bbase = (mat * 2) * 4096 + kc * 2048 + q16 * 512
                                        + (nt * 16 + l15) * 8;
                        bf16x8 whi = *(const bf16x8*)&wLDS[bbase];
                        bf16x8 wlo = *(const bf16x8*)&wLDS[bbase + 4096];
#pragma unroll
                        for (int tile = 0; tile < 4; ++tile) {
                            acc[tile][mat][nt] = __builtin_amdgcn_mfma_f32_16x16x32_bf16(
                                ah[tile], whi, acc[tile][mat][nt], 0, 0, 0);
                            acc[tile][mat][nt] = __builtin_amdgcn_mfma_f32_16x16x32_bf16(
                                al[tile], whi, acc[tile][mat][nt], 0, 0, 0);
                            acc[tile][mat][nt] = __builtin_amdgcn_mfma_f32_16x16x32_bf16(
                                ah[tile], wlo, acc[tile][mat][nt], 0, 0, 0);
                        }
                    }
            }
        }

        // epilogue for this d-chunk: C mapping col=lane&15 (d), row=q16*4+reg
#pragma unroll
        for (int nt = 0; nt < 4; ++nt) {
            const int dd = dg + nt * 16 + l15;
            const float bnv = bn[dd], bgv = bg[dd], wlv = Wl[dd];
            const float rvv = Rg[(size_t)j * DIM + dd];
#pragma unroll
            for (int tile = 0; tile < 4; ++tile) {
#pragma unroll
                for (int reg = 0; reg < 4; ++reg) {
                    const int i = i0 + tile * 16 + q16 * 4 + reg;
                    float h  = fmaxf(acc[tile][0][nt][reg] + bnv, 0.f);
                    float g  = 1.f / (1.f + __expf(-(acc[tile][1][nt][reg] + bgv)));
                    float cc = fabsf(Lg[(size_t)i * DIM + dd] - rvv);
                    sacc[tile][reg] = fmaf(wlv, fmaf(g, h - cc, cc), sacc[tile][reg]);
                }
            }
        }
    }

    // reduce over the 16 lanes sharing q16 (the d direction), then write
#pragma unroll
    for (int tile = 0; tile < 4; ++tile)
#pragma unroll
        for (int reg = 0; reg < 4; ++reg) {
            float v = sacc[tile][reg];
            v += __shfl_xor(v, 1); v += __shfl_xor(v, 2);
            v += __shfl_xor(v, 4); v += __shfl_xor(v, 8);
            if (l15 == 0)
                scores[(size_t)(i0 + tile * 16 + q16 * 4 + reg) * RTOK + j] = v;
        }
}

// ---------------------------------------------------------------------------
// Kernel 2: argmax per row (left) and per column (right); first-occurrence ties.
// ---------------------------------------------------------------------------
__global__ __launch_bounds__(64) void argmax_kernel(
    const float* __restrict__ scores, int* __restrict__ idxL, int* __restrict__ idxR)
{
    const int b = blockIdx.x;          // 0..511 rows, 512..1023 cols
    const int t = threadIdx.x;
    const bool isRow = (b < LTOK);
    const int  n = b & (LTOK - 1);

    float best = -INFINITY;
    int   bidx = 0x7fffffff;
    for (int s = t; s < 512; s += 64) {
        float v = isRow ? scores[n * RTOK + s] : scores[s * RTOK + n];
        if (v > best) { best = v; bidx = s; }
    }
#pragma unroll
    for (int off = 32; off; off >>= 1) {
        float ob = __shfl_down(best, off);
        int   oi = __shfl_down(bidx, off);
        if (ob > best || (ob == best && oi < bidx)) { best = ob; bidx = oi; }
    }
    if (t == 0) (isRow ? idxL : idxR)[n] = bidx;
}

// ---------------------------------------------------------------------------
// Kernel 3: gather chosen cmp rows.
// ---------------------------------------------------------------------------
__global__ __launch_bounds__(256) void build_cmp_kernel(
    const float* __restrict__ Lg, const float* __restrict__ Rg,
    const int* __restrict__ idxL, const int* __restrict__ idxR,
    float* __restrict__ lcmp, float* __restrict__ rcmp)
{
    const int b = blockIdx.x;
    const int t = threadIdx.x;
    if (b < LTOK) {
        const float* a = Lg + b * DIM;
        const float* c = Rg + idxL[b] * DIM;
        for (int d = t; d < DIM; d += 256) lcmp[b * DIM + d] = fabsf(a[d] - c[d]);
    } else {
        const int jj = b - LTOK;
        const float* a = Rg + jj * DIM;
        const float* c = Lg + idxR[jj] * DIM;
        for (int d = t; d < DIM; d += 256) rcmp[jj * DIM + d] = fabsf(a[d] - c[d]);
    }
}

// ---------------------------------------------------------------------------
// Kernel 4: attribute matching (ragged segment softmax + weighted cmp sum).
// ---------------------------------------------------------------------------
__global__ __launch_bounds__(256) void attr_match_kernel(
    const float* __restrict__ Lg, const float* __restrict__ Rg,
    const float* __restrict__ lcmp, const float* __restrict__ rcmp,
    const int* __restrict__ lensL, const int* __restrict__ lensR,
    const float* __restrict__ embL, const float* __restrict__ embR,
    const float* __restrict__ emptyRes,
    float* __restrict__ x)
{
    __shared__ float logits[512];
    __shared__ float red[256];

    const int b    = blockIdx.x;
    const int side = b >> 3;
    const int a    = b & 7;
    const int t    = threadIdx.x;

    const int*   lens = side ? lensR : lensL;
    const float* toks = side ? Rg   : Lg;
    const float* cmp  = side ? rcmp : lcmp;
    const float* femb = (side ? embR : embL) + a * DIM;
    float* outp = x + (side * 8 + a) * DIM;

    int start = 0;
    for (int q = 0; q < a; ++q) start += lens[q];
    const int len = lens[a];

    if (len == 0) {
        for (int d = t; d < DIM; d += 256) outp[d] = emptyRes[d];
        return;
    }

    for (int tok = t; tok < len; tok += 256) {
        const float* tr = toks + (start + tok) * DIM;
        float s = 0.f;
        for (int d = 0; d < DIM; ++d) s = fmaf(tr[d], femb[d], s);
        logits[tok] = s;
    }
    __syncthreads();

    float m = -INFINITY;
    for (int tok = t; tok < len; tok += 256) m = fmaxf(m, logits[tok]);
    red[t] = m; __syncthreads();
    for (int off = 128; off; off >>= 1) {
        if (t < off) red[t] = fmaxf(red[t], red[t + off]);
        __syncthreads();
    }
    m = red[0]; __syncthreads();

    float sum = 0.f;
    for (int tok = t; tok < len; tok += 256) {
        float e = expf(logits[tok] - m);
        logits[tok] = e;
        sum += e;
    }
    red[t] = sum; __syncthreads();
    for (int off = 128; off; off >>= 1) {
        if (t < off) red[t] += red[t + off];
        __syncthreads();
    }
    const float inv = 1.f / red[0];
    __syncthreads();

    for (int d = t; d < DIM; d += 256) {
        float accv = 0.f;
        for (int tok = 0; tok < len; ++tok)
            accv = fmaf(logits[tok] * inv, cmp[(start + tok) * DIM + d], accv);
        outp[d] = accv;
    }
}

// ---------------------------------------------------------------------------
// Kernel 5: entity highway matvec partials (split-K, deterministic).
// ---------------------------------------------------------------------------
__global__ __launch_bounds__(256) void ent_partial_kernel(
    const float* __restrict__ Wn, const float* __restrict__ Wg,
    const float* __restrict__ x, float* __restrict__ partial)
{
    __shared__ float xs[384];
    const int ob   = blockIdx.x;   // 12
    const int slab = blockIdx.y;   // 32
    const int mat  = blockIdx.z;   // 2
    const float* W = mat ? Wg : Wn;
    const int t  = threadIdx.x;
    const int o0 = ob * 1024 + t * 4;
    const int in0 = slab * 384;

    for (int i = t; i < 384; i += 256) xs[i] = x[in0 + i];
    __syncthreads();

    float4 acc = {0.f, 0.f, 0.f, 0.f};
    for (int in = 0; in < 384; ++in) {
        const float  xv = xs[in];
        const float4 w  = *(const float4*)(W + (size_t)(in0 + in) * EDIM + o0);
        acc.x = fmaf(xv, w.x, acc.x);
        acc.y = fmaf(xv, w.y, acc.y);
        acc.z = fmaf(xv, w.z, acc.z);
        acc.w = fmaf(xv, w.w, acc.w);
    }
    *(float4*)(partial + ((size_t)mat * 32 + slab) * EDIM + o0) = acc;
}

// ---------------------------------------------------------------------------
// Kernel 6: reduce the 32 split-K partials.
// ---------------------------------------------------------------------------
__global__ __launch_bounds__(256) void ent_reduce_kernel(
    const float* __restrict__ partial, float* __restrict__ hsum)
{
    const int mat = blockIdx.y;
    const int o   = blockIdx.x * 1024 + threadIdx.x * 4;
    float4 acc = {0.f, 0.f, 0.f, 0.f};
    for (int s = 0; s < 32; ++s) {
        const float4 p = *(const float4*)(partial + ((size_t)mat * 32 + s) * EDIM + o);
        acc.x += p.x; acc.y += p.y; acc.z += p.z; acc.w += p.w;
    }
    *(float4*)(hsum + (size_t)mat * EDIM + o) = acc;
}

// ---------------------------------------------------------------------------
// Kernel 7: entity highway epilogue + final linear + softmax.
// ---------------------------------------------------------------------------
__global__ __launch_bounds__(256) void finalize_kernel(
    const float* __restrict__ hsum, const float* __restrict__ x,
    const float* __restrict__ bn, const float* __restrict__ bg,
    const float* __restrict__ Wl2, const float* __restrict__ bl2,
    float* __restrict__ out)
{
    __shared__ float r0[256], r1[256];
    const int t = threadIdx.x;
    float l0 = 0.f, l1 = 0.f;
    for (int d = t; d < EDIM; d += 256) {
        float h  = fmaxf(hsum[d] + bn[d], 0.f);
        float gv = 1.f / (1.f + expf(-(hsum[EDIM + d] + bg[d])));
        float hw = gv * h + (1.f - gv) * x[d];
        l0 = fmaf(hw, Wl2[d * 2 + 0], l0);
        l1 = fmaf(hw, Wl2[d * 2 + 1], l1);
    }
    r0[t] = l0; r1[t] = l1; __syncthreads();
    for (int off = 128; off; off >>= 1) {
        if (t < off) { r0[t] += r0[t + off]; r1[t] += r1[t + off]; }
        __syncthreads();
    }
    if (t == 0) {
        float a = r0[0] + bl2[0];
        float b = r1[0] + bl2[1];
        float m  = fmaxf(a, b);
        float ea = expf(a - m), eb = expf(b - m);
        float inv = 1.f / (ea + eb);
        out[0] = ea * inv;
        out[1] = eb * inv;
    }
}

// ---------------------------------------------------------------------------
extern "C" void kernel_launch(void* const* d_in, const int* in_sizes, int n_in,
                              void* d_out, int out_size, void* d_ws, size_t ws_size,
                              hipStream_t stream)
{
    const float* Lg     = (const float*)d_in[0];
    const float* Rg     = (const float*)d_in[1];
    const int*   lensL  = (const int*)  d_in[2];
    const int*   lensR  = (const int*)  d_in[3];
    const float* tWn    = (const float*)d_in[4];
    const float* tbn    = (const float*)d_in[5];
    const float* tWg    = (const float*)d_in[6];
    const float* tbg    = (const float*)d_in[7];
    const float* tWl    = (const float*)d_in[8];
    // d_in[9] = lin_tok_b : constant score shift, irrelevant to argmax
    const float* embL   = (const float*)d_in[10];
    const float* embR   = (const float*)d_in[11];
    const float* eWn    = (const float*)d_in[12];
    const float* ebn    = (const float*)d_in[13];
    const float* eWg    = (const float*)d_in[14];
    const float* ebg    = (const float*)d_in[15];
    const float* eWl    = (const float*)d_in[16];
    const float* ebl    = (const float*)d_in[17];
    const float* emptyR = (const float*)d_in[18];
    float* out = (float*)d_out;

    // workspace layout (bytes) — total 5.92 MB (proven-safe range):
    //   [0, 4718592)        wsplit (4 x 768^2 bf16)   — dead after scores_kernel
    //     aliased later: lcmp [0,1.5M) + rcmp [1.5M,3M) — dead after attr_match
    //     aliased later: ent partial [0, 3M)
    //   [4718592, +1MB)     scores
    //   [5767168, +4KB)     idxL/idxR
    //   [5771264, +48KB)    xcat
    //   [5820416, +96KB)    hsum
    char* ws = (char*)d_ws;
    u16*   wsplit  = (u16*)ws;
    float* scores  = (float*)(ws + 4718592);
    int*   idxL    = (int*)(ws + 5767168);
    int*   idxR    = idxL + 512;
    float* xcat    = (float*)(ws + 5771264);
    float* hsum    = (float*)(ws + 5820416);
    float* lcmp    = (float*)ws;
    float* rcmp    = lcmp + (size_t)LTOK * DIM;
    float* partial = (float*)ws;

    wsplit_kernel<<<dim3(3, 768), 256, 0, stream>>>(tWn, tWg, wsplit);

    scores_kernel<<<dim3(LTOK / 64, RTOK / 4), 256, 0, stream>>>(
        Lg, Rg, wsplit, tbn, tbg, tWl, scores);

    argmax_kernel<<<dim3(LTOK + RTOK), 64, 0, stream>>>(scores, idxL, idxR);

    build_cmp_kernel<<<dim3(LTOK + RTOK), 256, 0, stream>>>(
        Lg, Rg, idxL, idxR, lcmp, rcmp);

    attr_match_kernel<<<dim3(16), 256, 0, stream>>>(
        Lg, Rg, lcmp, rcmp, lensL, lensR, embL, embR, emptyR, xcat);

    ent_partial_kernel<<<dim3(EDIM / 1024, 32, 2), 256, 0, stream>>>(
        eWn, eWg, xcat, partial);

    ent_reduce_kernel<<<dim3(EDIM / 1024, 2), 256, 0, stream>>>(partial, hsum);

    finalize_kernel<<<dim3(1), 256, 0, stream>>>(
        hsum, xcat, ebn, ebg, eWl, ebl, out);
}

// Round 5
// 2233.813 us; speedup vs baseline: 7.3680x; 1.0818x over previous
//
#include <hip/hip_runtime.h>
#include <cmath>

#define NL 8
#define NR 8
#define DIM 768
#define LTOK 512
#define RTOK 512
#define EDIM 12288   // (NL+NR)*DIM
#define KST 32       // K per pipeline stage

typedef unsigned short u16;
typedef __bf16 bf16x8 __attribute__((ext_vector_type(8)));
typedef float  f32x16 __attribute__((ext_vector_type(16)));

#define WARR 589824          // 768*768 elements per split array
// frag-major layout for W (per array): idx(k,d) = ((k>>3)*768 + d)*8 + (k&7)
// (k8-group major; shape-agnostic for both 16x16x32 and 32x32x16 B-fragments)

// RNE split of f32 into bf16 hi + bf16 lo (x ~= hi + lo; residual exact in f32)
__device__ __forceinline__ void splitbf(float c, u16& hi, u16& lo) {
    __bf16 h = (__bf16)c;
    __bf16 l = (__bf16)(c - (float)h);
    hi = __builtin_bit_cast(u16, h);
    lo = __builtin_bit_cast(u16, l);
}

__device__ __forceinline__ void gll16(const void* gsrc, void* lds) {
    __builtin_amdgcn_global_load_lds(
        (const __attribute__((address_space(1))) unsigned int*)gsrc,
        (__attribute__((address_space(3))) unsigned int*)lds, 16, 0, 0);
}

// ---------------------------------------------------------------------------
// Kernel 0: pre-split token-matching weights into bf16 hi/lo, frag-major.
// out: [wn_hi | wn_lo | wg_hi | wg_lo], each WARR u16.
// Thread (d, kg): 8 strided-coalesced reads, one 16B contiguous write per arr.
// ---------------------------------------------------------------------------
__global__ __launch_bounds__(256) void wsplit_kernel(
    const float* __restrict__ Wn, const float* __restrict__ Wg, u16* __restrict__ out)
{
    const int gid = blockIdx.x * 256 + threadIdx.x;   // 768 d x 96 kg = 73728
    const int d  = gid % DIM;
    const int kg = gid / DIM;
    u16 hn[8], ln[8], hg[8], lg2[8];
#pragma unroll
    for (int e = 0; e < 8; ++e) {
        splitbf(Wn[(size_t)(kg * 8 + e) * DIM + d], hn[e], ln[e]);
        splitbf(Wg[(size_t)(kg * 8 + e) * DIM + d], hg[e], lg2[e]);
    }
    const size_t fo = ((size_t)kg * DIM + d) * 8;
    *(uint4*)&out[fo]            = *(uint4*)hn;
    *(uint4*)&out[WARR + fo]     = *(uint4*)ln;
    *(uint4*)&out[2 * WARR + fo] = *(uint4*)hg;
    *(uint4*)&out[3 * WARR + fo] = *(uint4*)lg2;
}

// ---------------------------------------------------------------------------
// Kernel 1: token-matching scores via bf16x3 split MFMA (32x32x16).
//   hacc[p][d] = sum_k |l_i[k]-r_j[k]| * Wn[k][d]   (+ same for Wg)
//   score[p]   = sum_d Wl[d] * highway_d(...)
//
// Block: 256 thr = 4 waves; wave = 1 j-column, 64 i-rows as 2 A-tiles of 32.
// D swept in chunks of 64 (12 sweeps); K double-buffer-staged 32 per stage.
// W frags via global_load_lds (linear LDS), lT via reg staging, rT resident.
// ---------------------------------------------------------------------------
__global__ __launch_bounds__(256, 2) void scores_kernel(
    const float* __restrict__ Lg, const float* __restrict__ Rg,
    const u16* __restrict__ wfrag,
    const float* __restrict__ bn, const float* __restrict__ bg,
    const float* __restrict__ Wl,
    float* __restrict__ scores)
{
    __shared__ u16   wLDS[2][8192];     // [buf][arr4][kg4][d64][e8]  16KB/buf
    __shared__ float lT[2][64][34];     // [buf][i-row][k32 + pad2]
    __shared__ float rT[4][768];        // [j-row][full K]

    const int t    = threadIdx.x;
    const int lane = t & 63;
    const int wid  = t >> 6;
    const int l31  = lane & 31;
    const int kh   = lane >> 5;
    const int i0   = blockIdx.x * 64;
    const int j0   = blockIdx.y * 4;
    const int j    = j0 + wid;

    const int rowS = t >> 2;            // lT staging: row per thread
    const int cS   = (t & 3) * 8;       // 8 floats per thread

    // ---- prologue: rT full-K + stage 0 into buf 0 ----
#pragma unroll
    for (int it = 0; it < 3; ++it) {
        int idx = it * 256 + t;                 // float4 idx 0..767
        int row = idx / 192;
        int c4  = (idx - row * 192) * 4;
        *(float4*)&rT[row][c4] = *(const float4*)(Rg + (size_t)(j0 + row) * DIM + c4);
    }
    {
#pragma unroll
        for (int it = 0; it < 4; ++it) {
            int chunk = it * 4 + wid;           // 0..15
            int arr = chunk >> 2, kg = chunk & 3;
            const u16* src = wfrag + (size_t)arr * WARR + ((size_t)kg * DIM + lane) * 8;
            gll16(src, &wLDS[0][chunk * 512]);
        }
        float4 a0 = *(const float4*)(Lg + (size_t)(i0 + rowS) * DIM + cS);
        float4 a1 = *(const float4*)(Lg + (size_t)(i0 + rowS) * DIM + cS + 4);
        float* dst = &lT[0][rowS][cS];
        *(float2*)(dst + 0) = make_float2(a0.x, a0.y);
        *(float2*)(dst + 2) = make_float2(a0.z, a0.w);
        *(float2*)(dst + 4) = make_float2(a1.x, a1.y);
        *(float2*)(dst + 6) = make_float2(a1.z, a1.w);
    }
    __syncthreads();

    float sacc[2][16];
#pragma unroll
    for (int tile = 0; tile < 2; ++tile)
#pragma unroll
        for (int r = 0; r < 16; ++r) sacc[tile][r] = 0.f;

    f32x16 acc[2][2][2];                        // [tile][mat][nd]
#pragma unroll
    for (int tile = 0; tile < 2; ++tile)
#pragma unroll
        for (int mat = 0; mat < 2; ++mat)
#pragma unroll
            for (int nd = 0; nd < 2; ++nd)
                for (int r = 0; r < 16; ++r) acc[tile][mat][nd][r] = 0.f;

    int buf = 0, k0 = 0, dg = 0;
    for (int s = 0; s < 288; ++s) {             // 12 sweeps x 24 k-stages
        int k0n = k0 + KST, dgn = dg;
        const bool last = (k0n == DIM);
        if (last) { k0n = 0; dgn = dg + 64; }
        const bool pref = (s < 287);

        float4 a0, a1;
        if (pref) {
            // issue next-stage loads: W frags direct-to-LDS, lT to regs
            const int kgb = k0n >> 3;
#pragma unroll
            for (int it = 0; it < 4; ++it) {
                int chunk = it * 4 + wid;
                int arr = chunk >> 2, kg = chunk & 3;
                const u16* src = wfrag + (size_t)arr * WARR +
                                 ((size_t)(kgb + kg) * DIM + dgn + lane) * 8;
                gll16(src, &wLDS[buf ^ 1][chunk * 512]);
            }
            a0 = *(const float4*)(Lg + (size_t)(i0 + rowS) * DIM + k0n + cS);
            a1 = *(const float4*)(Lg + (size_t)(i0 + rowS) * DIM + k0n + cS + 4);
        }

        // ---- compute current stage ----
        {
            const float* rrow = &rT[wid][k0 + kh * 8];
            const u16* wb = &wLDS[buf][0];
#pragma unroll
            for (int kk = 0; kk < 2; ++kk) {
                float rv[8];
#pragma unroll
                for (int e = 0; e < 8; e += 2) {
                    float2 p = *(const float2*)(rrow + kk * 16 + e);
                    rv[e] = p.x; rv[e + 1] = p.y;
                }
                bf16x8 ah[2], al[2];
#pragma unroll
                for (int tile = 0; tile < 2; ++tile) {
                    const float* lrow = &lT[buf][tile * 32 + l31][kk * 16 + kh * 8];
#pragma unroll
                    for (int e = 0; e < 8; e += 2) {
                        float2 lp = *(const float2*)(lrow + e);
                        float c0 = fabsf(lp.x - rv[e]);
                        float c1 = fabsf(lp.y - rv[e + 1]);
                        __bf16 h0 = (__bf16)c0, h1 = (__bf16)c1;
                        ah[tile][e]     = h0;
                        ah[tile][e + 1] = h1;
                        al[tile][e]     = (__bf16)(c0 - (float)h0);
                        al[tile][e + 1] = (__bf16)(c1 - (float)h1);
                    }
                }
#pragma unroll
                for (int mat = 0; mat < 2; ++mat)
#pragma unroll
                    for (int nd = 0; nd < 2; ++nd) {
                        const int base = (mat * 2) * 2048 + (kk * 2 + kh) * 512
                                       + (nd * 32 + l31) * 8;
                        bf16x8 whi = *(const bf16x8*)&wb[base];
                        bf16x8 wlo = *(const bf16x8*)&wb[base + 2048];
#pragma unroll
                        for (int tile = 0; tile < 2; ++tile) {
                            acc[tile][mat][nd] = __builtin_amdgcn_mfma_f32_32x32x16_bf16(
                                ah[tile], whi, acc[tile][mat][nd], 0, 0, 0);
                            acc[tile][mat][nd] = __builtin_amdgcn_mfma_f32_32x32x16_bf16(
                                al[tile], whi, acc[tile][mat][nd], 0, 0, 0);
                            acc[tile][mat][nd] = __builtin_amdgcn_mfma_f32_32x32x16_bf16(
                                ah[tile], wlo, acc[tile][mat][nd], 0, 0, 0);
                        }
                    }
            }
        }

        if (last) {
            // sweep epilogue: nonlinearity + score accumulation for d in [dg,dg+64)
            // C layout (32x32): col(d) = lane&31, row(i) = (reg&3)+8*(reg>>2)+4*kh
#pragma unroll
            for (int nd = 0; nd < 2; ++nd) {
                const int dd = dg + nd * 32 + l31;
                const float bnv = bn[dd], bgv = bg[dd], wlv = Wl[dd];
                const float rvv = Rg[(size_t)j * DIM + dd];
#pragma unroll
                for (int tile = 0; tile < 2; ++tile)
#pragma unroll
                    for (int r = 0; r < 16; ++r) {
                        const int m = (r & 3) + 8 * (r >> 2) + 4 * kh;
                        const int i = i0 + tile * 32 + m;
                        float h  = fmaxf(acc[tile][0][nd][r] + bnv, 0.f);
                        float g  = 1.f / (1.f + __expf(-(acc[tile][1][nd][r] + bgv)));
                        float cc = fabsf(Lg[(size_t)i * DIM + dd] - rvv);
                        sacc[tile][r] = fmaf(wlv, fmaf(g, h - cc, cc), sacc[tile][r]);
                    }
            }
#pragma unroll
            for (int tile = 0; tile < 2; ++tile)
#pragma unroll
                for (int mat = 0; mat < 2; ++mat)
#pragma unroll
                    for (int nd = 0; nd < 2; ++nd)
#pragma unroll
                        for (int r = 0; r < 16; ++r) acc[tile][mat][nd][r] = 0.f;
        }

        if (pref) {
            // late write of prefetched lT regs (vmcnt ordered by data dep)
            float* dst = &lT[buf ^ 1][rowS][cS];
            *(float2*)(dst + 0) = make_float2(a0.x, a0.y);
            *(float2*)(dst + 2) = make_float2(a0.z, a0.w);
            *(float2*)(dst + 4) = make_float2(a1.x, a1.y);
            *(float2*)(dst + 6) = make_float2(a1.z, a1.w);
        }
        __syncthreads();
        buf ^= 1; k0 = k0n; dg = dgn;
    }

    // reduce sacc over the 32 lanes of each half (d direction), write scores
#pragma unroll
    for (int tile = 0; tile < 2; ++tile)
#pragma unroll
        for (int r = 0; r < 16; ++r) {
            float v = sacc[tile][r];
            v += __shfl_xor(v, 1);  v += __shfl_xor(v, 2);
            v += __shfl_xor(v, 4);  v += __shfl_xor(v, 8);
            v += __shfl_xor(v, 16);
            if (l31 == 0) {
                const int m = (r & 3) + 8 * (r >> 2) + 4 * kh;
                scores[(size_t)(i0 + tile * 32 + m) * RTOK + j] = v;
            }
        }
}

// ---------------------------------------------------------------------------
// Kernel 2: argmax per row (left) and per column (right); first-occurrence ties.
// ---------------------------------------------------------------------------
__global__ __launch_bounds__(64) void argmax_kernel(
    const float* __restrict__ scores, int* __restrict__ idxL, int* __restrict__ idxR)
{
    const int b = blockIdx.x;          // 0..511 rows, 512..1023 cols
    const int t = threadIdx.x;
    const bool isRow = (b < LTOK);
    const int  n = b & (LTOK - 1);

    float best = -INFINITY;
    int   bidx = 0x7fffffff;
    for (int s = t; s < 512; s += 64) {
        float v = isRow ? scores[n * RTOK + s] : scores[s * RTOK + n];
        if (v > best) { best = v; bidx = s; }
    }
#pragma unroll
    for (int off = 32; off; off >>= 1) {
        float ob = __shfl_down(best, off);
        int   oi = __shfl_down(bidx, off);
        if (ob > best || (ob == best && oi < bidx)) { best = ob; bidx = oi; }
    }
    if (t == 0) (isRow ? idxL : idxR)[n] = bidx;
}

// ---------------------------------------------------------------------------
// Kernel 3: gather chosen cmp rows.
// ---------------------------------------------------------------------------
__global__ __launch_bounds__(256) void build_cmp_kernel(
    const float* __restrict__ Lg, const float* __restrict__ Rg,
    const int* __restrict__ idxL, const int* __restrict__ idxR,
    float* __restrict__ lcmp, float* __restrict__ rcmp)
{
    const int b = blockIdx.x;
    const int t = threadIdx.x;
    if (b < LTOK) {
        const float* a = Lg + b * DIM;
        const float* c = Rg + idxL[b] * DIM;
        for (int d = t; d < DIM; d += 256) lcmp[b * DIM + d] = fabsf(a[d] - c[d]);
    } else {
        const int jj = b - LTOK;
        const float* a = Rg + jj * DIM;
        const float* c = Lg + idxR[jj] * DIM;
        for (int d = t; d < DIM; d += 256) rcmp[jj * DIM + d] = fabsf(a[d] - c[d]);
    }
}

// ---------------------------------------------------------------------------
// Kernel 4: attribute matching (ragged segment softmax + weighted cmp sum).
// ---------------------------------------------------------------------------
__global__ __launch_bounds__(256) void attr_match_kernel(
    const float* __restrict__ Lg, const float* __restrict__ Rg,
    const float* __restrict__ lcmp, const float* __restrict__ rcmp,
    const int* __restrict__ lensL, const int* __restrict__ lensR,
    const float* __restrict__ embL, const float* __restrict__ embR,
    const float* __restrict__ emptyRes,
    float* __restrict__ x)
{
    __shared__ float logits[512];
    __shared__ float red[256];

    const int b    = blockIdx.x;
    const int side = b >> 3;
    const int a    = b & 7;
    const int t    = threadIdx.x;

    const int*   lens = side ? lensR : lensL;
    const float* toks = side ? Rg   : Lg;
    const float* cmp  = side ? rcmp : lcmp;
    const float* femb = (side ? embR : embL) + a * DIM;
    float* outp = x + (side * 8 + a) * DIM;

    int start = 0;
    for (int q = 0; q < a; ++q) start += lens[q];
    const int len = lens[a];

    if (len == 0) {
        for (int d = t; d < DIM; d += 256) outp[d] = emptyRes[d];
        return;
    }

    for (int tok = t; tok < len; tok += 256) {
        const float* tr = toks + (start + tok) * DIM;
        float s = 0.f;
        for (int d = 0; d < DIM; ++d) s = fmaf(tr[d], femb[d], s);
        logits[tok] = s;
    }
    __syncthreads();

    float m = -INFINITY;
    for (int tok = t; tok < len; tok += 256) m = fmaxf(m, logits[tok]);
    red[t] = m; __syncthreads();
    for (int off = 128; off; off >>= 1) {
        if (t < off) red[t] = fmaxf(red[t], red[t + off]);
        __syncthreads();
    }
    m = red[0]; __syncthreads();

    float sum = 0.f;
    for (int tok = t; tok < len; tok += 256) {
        float e = expf(logits[tok] - m);
        logits[tok] = e;
        sum += e;
    }
    red[t] = sum; __syncthreads();
    for (int off = 128; off; off >>= 1) {
        if (t < off) red[t] += red[t + off];
        __syncthreads();
    }
    const float inv = 1.f / red[0];
    __syncthreads();

    for (int d = t; d < DIM; d += 256) {
        float accv = 0.f;
        for (int tok = 0; tok < len; ++tok)
            accv = fmaf(logits[tok] * inv, cmp[(start + tok) * DIM + d], accv);
        outp[d] = accv;
    }
}

// ---------------------------------------------------------------------------
// Kernel 5: entity highway matvec partials (split-K, deterministic).
// ---------------------------------------------------------------------------
__global__ __launch_bounds__(256) void ent_partial_kernel(
    const float* __restrict__ Wn, const float* __restrict__ Wg,
    const float* __restrict__ x, float* __restrict__ partial)
{
    __shared__ float xs[384];
    const int ob   = blockIdx.x;   // 12
    const int slab = blockIdx.y;   // 32
    const int mat  = blockIdx.z;   // 2
    const float* W = mat ? Wg : Wn;
    const int t  = threadIdx.x;
    const int o0 = ob * 1024 + t * 4;
    const int in0 = slab * 384;

    for (int i = t; i < 384; i += 256) xs[i] = x[in0 + i];
    __syncthreads();

    float4 acc = {0.f, 0.f, 0.f, 0.f};
    for (int in = 0; in < 384; ++in) {
        const float  xv = xs[in];
        const float4 w  = *(const float4*)(W + (size_t)(in0 + in) * EDIM + o0);
        acc.x = fmaf(xv, w.x, acc.x);
        acc.y = fmaf(xv, w.y, acc.y);
        acc.z = fmaf(xv, w.z, acc.z);
        acc.w = fmaf(xv, w.w, acc.w);
    }
    *(float4*)(partial + ((size_t)mat * 32 + slab) * EDIM + o0) = acc;
}

// ---------------------------------------------------------------------------
// Kernel 6: reduce the 32 split-K partials.
// ---------------------------------------------------------------------------
__global__ __launch_bounds__(256) void ent_reduce_kernel(
    const float* __restrict__ partial, float* __restrict__ hsum)
{
    const int mat = blockIdx.y;
    const int o   = blockIdx.x * 1024 + threadIdx.x * 4;
    float4 acc = {0.f, 0.f, 0.f, 0.f};
    for (int s = 0; s < 32; ++s) {
        const float4 p = *(const float4*)(partial + ((size_t)mat * 32 + s) * EDIM + o);
        acc.x += p.x; acc.y += p.y; acc.z += p.z; acc.w += p.w;
    }
    *(float4*)(hsum + (size_t)mat * EDIM + o) = acc;
}

// ---------------------------------------------------------------------------
// Kernel 7: entity highway epilogue + final linear + softmax.
// ---------------------------------------------------------------------------
__global__ __launch_bounds__(256) void finalize_kernel(
    const float* __restrict__ hsum, const float* __restrict__ x,
    const float* __restrict__ bn, const float* __restrict__ bg,
    const float* __restrict__ Wl2, const float* __restrict__ bl2,
    float* __restrict__ out)
{
    __shared__ float r0[256], r1[256];
    const int t = threadIdx.x;
    float l0 = 0.f, l1 = 0.f;
    for (int d = t; d < EDIM; d += 256) {
        float h  = fmaxf(hsum[d] + bn[d], 0.f);
        float gv = 1.f / (1.f + expf(-(hsum[EDIM + d] + bg[d])));
        float hw = gv * h + (1.f - gv) * x[d];
        l0 = fmaf(hw, Wl2[d * 2 + 0], l0);
        l1 = fmaf(hw, Wl2[d * 2 + 1], l1);
    }
    r0[t] = l0; r1[t] = l1; __syncthreads();
    for (int off = 128; off; off >>= 1) {
        if (t < off) { r0[t] += r0[t + off]; r1[t] += r1[t + off]; }
        __syncthreads();
    }
    if (t == 0) {
        float a = r0[0] + bl2[0];
        float b = r1[0] + bl2[1];
        float m  = fmaxf(a, b);
        float ea = expf(a - m), eb = expf(b - m);
        float inv = 1.f / (ea + eb);
        out[0] = ea * inv;
        out[1] = eb * inv;
    }
}

// ---------------------------------------------------------------------------
extern "C" void kernel_launch(void* const* d_in, const int* in_sizes, int n_in,
                              void* d_out, int out_size, void* d_ws, size_t ws_size,
                              hipStream_t stream)
{
    const float* Lg     = (const float*)d_in[0];
    const float* Rg     = (const float*)d_in[1];
    const int*   lensL  = (const int*)  d_in[2];
    const int*   lensR  = (const int*)  d_in[3];
    const float* tWn    = (const float*)d_in[4];
    const float* tbn    = (const float*)d_in[5];
    const float* tWg    = (const float*)d_in[6];
    const float* tbg    = (const float*)d_in[7];
    const float* tWl    = (const float*)d_in[8];
    // d_in[9] = lin_tok_b : constant score shift, irrelevant to argmax
    const float* embL   = (const float*)d_in[10];
    const float* embR   = (const float*)d_in[11];
    const float* eWn    = (const float*)d_in[12];
    const float* ebn    = (const float*)d_in[13];
    const float* eWg    = (const float*)d_in[14];
    const float* ebg    = (const float*)d_in[15];
    const float* eWl    = (const float*)d_in[16];
    const float* ebl    = (const float*)d_in[17];
    const float* emptyR = (const float*)d_in[18];
    float* out = (float*)d_out;

    // workspace layout (bytes):
    //   [0, 4718592)        wsplit (4 x 768^2 bf16)   — dead after scores_kernel
    //     aliased later: lcmp [0,1.5M) + rcmp [1.5M,3M) — dead after attr_match
    //     aliased later: ent partial [0, 3M)
    //   [4718592, +1MB)     scores
    //   [5767168, +4KB)     idxL/idxR
    //   [5771264, +48KB)    xcat
    //   [5820416, +96KB)    hsum
    char* ws = (char*)d_ws;
    u16*   wsplit  = (u16*)ws;
    float* scores  = (float*)(ws + 4718592);
    int*   idxL    = (int*)(ws + 5767168);
    int*   idxR    = idxL + 512;
    float* xcat    = (float*)(ws + 5771264);
    float* hsum    = (float*)(ws + 5820416);
    float* lcmp    = (float*)ws;
    float* rcmp    = lcmp + (size_t)LTOK * DIM;
    float* partial = (float*)ws;

    wsplit_kernel<<<dim3(288), 256, 0, stream>>>(tWn, tWg, wsplit);

    scores_kernel<<<dim3(LTOK / 64, RTOK / 4), 256, 0, stream>>>(
        Lg, Rg, wsplit, tbn, tbg, tWl, scores);

    argmax_kernel<<<dim3(LTOK + RTOK), 64, 0, stream>>>(scores, idxL, idxR);

    build_cmp_kernel<<<dim3(LTOK + RTOK), 256, 0, stream>>>(
        Lg, Rg, idxL, idxR, lcmp, rcmp);

    attr_match_kernel<<<dim3(16), 256, 0, stream>>>(
        Lg, Rg, lcmp, rcmp, lensL, lensR, embL, embR, emptyR, xcat);

    ent_partial_kernel<<<dim3(EDIM / 1024, 32, 2), 256, 0, stream>>>(
        eWn, eWg, xcat, partial);

    ent_reduce_kernel<<<dim3(EDIM / 1024, 2), 256, 0, stream>>>(partial, hsum);

    finalize_kernel<<<dim3(1), 256, 0, stream>>>(
        hsum, xcat, ebn, ebg, eWl, ebl, out);
}